// Round 7
// baseline (1141.256 us; speedup 1.0000x reference)
//
#include <hip/hip_runtime.h>
#include <stdint.h>

#define T_LEN 256
#define BATCH 64
#define EDIM  512
#define HDIM  256      // hidden per direction
#define GDIM  1024     // 4*HDIM
#define KTAG  7
#define NEGV  -10000.0f

using u16 = unsigned short;
using u32 = unsigned int;
using u64 = unsigned long long;

typedef short    bf16x8 __attribute__((ext_vector_type(8)));
typedef float    f32x4  __attribute__((ext_vector_type(4)));

__device__ __forceinline__ float bflo(u32 u) { return __uint_as_float(u << 16); }
__device__ __forceinline__ float bfhi(u32 u) { return __uint_as_float(u & 0xffff0000u); }
__device__ __forceinline__ float bf2f(u16 u) { return __uint_as_float(((u32)u) << 16); }
__device__ __forceinline__ u16 f2bf(float f) {
    u32 x = __float_as_uint(f);
    u32 r = x + 0x7fffu + ((x >> 16) & 1u);   // round-to-nearest-even
    return (u16)(r >> 16);
}
__device__ __forceinline__ u32 pack2(float a, float b) {
    return (u32)f2bf(a) | ((u32)f2bf(b) << 16);
}
// fast sigmoid / tanh (rel err ~1e-5, far below bf16 input noise)
__device__ __forceinline__ float fsig(float x)  { return __builtin_amdgcn_rcpf(1.f + __expf(-x)); }
__device__ __forceinline__ float ftanh(float x) { return 1.f - 2.f * __builtin_amdgcn_rcpf(1.f + __expf(2.f * x)); }

__device__ __forceinline__ int dot4i8(int a, int b, int c) {
#if __has_builtin(__builtin_amdgcn_sdot4)
    return __builtin_amdgcn_sdot4(a, b, c, false);     // v_dot4_i32_i8 (HW path confirmed R6)
#else
    c += (int)(signed char)(a & 0xff)         * (int)(signed char)(b & 0xff);
    c += (int)(signed char)((a >> 8) & 0xff)  * (int)(signed char)((b >> 8) & 0xff);
    c += (int)(signed char)((a >> 16) & 0xff) * (int)(signed char)((b >> 16) & 0xff);
    c += (int)(signed char)(a >> 24)          * (int)(signed char)(b >> 24);
    return c;
#endif
}

// ---------- fused preprocessing: embed gather | w_ih f32->bf16 | w_hh int8 quant ----------
// grid 5136 x 256: [0,4096) embed (4 tb/block), [4096,5120) conv_wih, [5120,5136) repack_whh_i8
__global__ __launch_bounds__(256) void prep_k(const int* __restrict__ sent,
                                              const float* __restrict__ emb,
                                              u16* __restrict__ X,
                                              const float* __restrict__ Wih,
                                              u16* __restrict__ WB,
                                              const float* __restrict__ Whh,
                                              uint4* __restrict__ WQ,
                                              float* __restrict__ SCL) {
    const int blk = blockIdx.x, tid = threadIdx.x;
    if (blk < 4096) {                                // ---- embedding gather+convert ----
        int tb   = blk * 4 + (tid >> 6);
        int lane = tid & 63;
        int tok  = sent[tb];
        const float4* src = (const float4*)(emb + (size_t)tok * EDIM);
        float4 a = src[lane * 2];
        float4 b = src[lane * 2 + 1];
        uint4 o;
        o.x = pack2(a.x, a.y); o.y = pack2(a.z, a.w);
        o.z = pack2(b.x, b.y); o.w = pack2(b.z, b.w);
        ((uint4*)(X + (size_t)tb * EDIM))[lane] = o;
    } else if (blk < 5120) {                         // ---- w_ih f32 -> bf16 ----
        int g = (blk - 4096) * 256 + tid;            // 262144 groups of 8
        const float4* src = (const float4*)(Wih + (size_t)g * 8);
        float4 a = src[0], b = src[1];
        uint4 o;
        o.x = pack2(a.x, a.y); o.y = pack2(a.z, a.w);
        o.z = pack2(b.x, b.y); o.w = pack2(b.z, b.w);
        *(uint4*)(WB + (size_t)g * 8) = o;
    } else {                                         // ---- w_hh int8 row-quant ----
        int g  = (blk - 5120) * 256 + tid;           // 4096 rows
        int ld = g >> 10, row = g & 1023;
        const float* src = Whh + ((size_t)ld * GDIM + row) * HDIM;
        float m = 1e-30f;
        for (int k4 = 0; k4 < 64; ++k4) {
            float4 w = ((const float4*)src)[k4];
            m = fmaxf(m, fmaxf(fmaxf(fabsf(w.x), fabsf(w.y)), fmaxf(fabsf(w.z), fabsf(w.w))));
        }
        float inv = 127.f / m;
        SCL[ld * GDIM + row] = m / 127.f;
        int r = row >> 8, j = row & 255;
        for (int c8 = 0; c8 < 16; ++c8) {            // 16-byte chunks
            u32 dw[4];
            #pragma unroll
            for (int d4 = 0; d4 < 4; ++d4) {
                u32 p = 0;
                #pragma unroll
                for (int bb = 0; bb < 4; ++bb) {
                    float w = src[c8 * 16 + d4 * 4 + bb];
                    int q = (int)rintf(w * inv);
                    q = q > 127 ? 127 : (q < -127 ? -127 : q);
                    p |= ((u32)(q & 0xff)) << (8 * bb);
                }
                dw[d4] = p;
            }
            int half = c8 >> 3, c = c8 & 7;
            WQ[(size_t)((((ld * 4 + r) * 2 + half) * 8 + c) * 256 + j)] =
                (uint4){dw[0], dw[1], dw[2], dw[3]};
        }
    }
}

// ------------- xg = x @ w_ih^T + b_ih + b_hh  (MFMA bf16, wave computes 64x64) -------------
// Block's 4 waves share the SAME A-tile (mi) -> identical A addresses hit L1; nj differs.
__global__ __launch_bounds__(256, 4) void gemm_xg(const u16* __restrict__ A,    // [16384][512] bf16
                                                  const u16* __restrict__ W,    // [2][1024][512] bf16
                                                  const float* __restrict__ Bih,// [2][1024] f32
                                                  const float* __restrict__ Bhh,
                                                  u16* __restrict__ XG) {       // [2][16384][1024] bf16
    const int d    = blockIdx.y;
    const int lane = threadIdx.x & 63;
    const int wv   = threadIdx.x >> 6;
    const int mi   = blockIdx.x >> 2;               // 0..255, shared by all 4 waves
    const int nj   = (blockIdx.x & 3) * 4 + wv;     // 0..15
    const int l15  = lane & 15;
    const int quad = lane >> 4;

    const u16* Wd = W + (size_t)d * GDIM * EDIM;
    const u16* Ap[4];
    const u16* Bp[4];
    #pragma unroll
    for (int i = 0; i < 4; ++i) {
        Ap[i] = A  + (size_t)(mi * 64 + i * 16 + l15) * EDIM + quad * 8;
        Bp[i] = Wd + (size_t)(nj * 64 + i * 16 + l15) * EDIM + quad * 8;
    }

    f32x4 acc[4][4];
    #pragma unroll
    for (int mt = 0; mt < 4; ++mt)
        #pragma unroll
        for (int nt = 0; nt < 4; ++nt)
            acc[mt][nt] = (f32x4){0.f, 0.f, 0.f, 0.f};

    for (int kk = 0; kk < 16; ++kk) {
        bf16x8 av[4], bv[4];
        #pragma unroll
        for (int i = 0; i < 4; ++i) {
            av[i] = *(const bf16x8*)(Ap[i] + kk * 32);
            bv[i] = *(const bf16x8*)(Bp[i] + kk * 32);
        }
        #pragma unroll
        for (int mt = 0; mt < 4; ++mt)
            #pragma unroll
            for (int nt = 0; nt < 4; ++nt)
                acc[mt][nt] = __builtin_amdgcn_mfma_f32_16x16x32_bf16(av[mt], bv[nt], acc[mt][nt], 0, 0, 0);
    }

    u16* xgd = XG + (size_t)d * ((size_t)16384 * GDIM);
    #pragma unroll
    for (int nt = 0; nt < 4; ++nt) {
        int col = nj * 64 + nt * 16 + l15;          // C/D: col=lane&15, row=quad*4+reg
        float bias = Bih[d * GDIM + col] + Bhh[d * GDIM + col];
        #pragma unroll
        for (int mt = 0; mt < 4; ++mt) {
            int row0 = mi * 64 + mt * 16 + quad * 4;
            #pragma unroll
            for (int r = 0; r < 4; ++r)
                xgd[(size_t)(row0 + r) * GDIM + col] = f2bf(acc[mt][nt][r] + bias);
        }
    }
}

// ------------- recurrent scan, int8 register-resident weights, full-K rows -------------
// 128 blocks = (d,b); 1024 threads; thread tid owns gate-row tid over ALL K=256:
// 16 uint4 = 64 VGPRs of weights, no split-K partials. 16 waves hide latency.
// Per step: coalesced 1024-wide xg row load, broadcast h reads, 64 dot4 in 4 chains,
// act via 4KB LDS, tid<256 do the c/h update. 2 barriers/step.
__global__ __launch_bounds__(1024, 4) void lstm_scan_i8(
        const u16* __restrict__ XG,        // [2][16384][1024] bf16 (this layer)
        const uint4* __restrict__ WQ,      // this layer's int8 slice (base at ld=2l)
        const float* __restrict__ SCL,     // [2][1024] weight LSB
        const float* __restrict__ H0,      // [2][64][256] f32
        const float* __restrict__ C0,
        u16* __restrict__ XOUT) {          // [16384][512] bf16
    const int b   = blockIdx.x & 63;
    const int d   = blockIdx.x >> 6;
    const int tid = threadIdx.x;
    const int r   = tid >> 8;              // gate (0..3)
    const int j   = tid & 255;             // hidden index within gate

    __shared__ uint4 hq[2][16];            // double-buffered int8 h (2 x 256 B)
    __shared__ float act[GDIM];            // activations (4 KB)

    // ---- load full-K weights for row tid (coalesced in j per (r,half,c) chunk) ----
    uint4 Wr[16];
    #pragma unroll
    for (int half = 0; half < 2; ++half)
        #pragma unroll
        for (int c = 0; c < 8; ++c)
            Wr[half * 8 + c] = WQ[(size_t)((((d * 4 + r) * 2 + half) * 8 + c) * 256 + j)];
    const float scl = SCL[d * GDIM + tid];

    // ---- init state ----
    float cst = 0.0f;
    if (tid < HDIM) {
        float h0v = H0[((size_t)d * BATCH + b) * HDIM + tid];
        cst       = C0[((size_t)d * BATCH + b) * HDIM + tid];
        int q = (int)rintf(h0v * 31.75f);                  // scale 127/4 (|h0| can exceed 1)
        q = q > 127 ? 127 : (q < -127 ? -127 : q);
        ((signed char*)hq)[tid] = (signed char)q;          // buffer 0
    }
    __syncthreads();

    const u16* xgp = XG + (size_t)d * ((size_t)16384 * GDIM) + (size_t)b * GDIM + tid;
    // 2-deep xg prefetch (all threads, fully coalesced 1024 x u16 rows)
    int t0 = d ? T_LEN - 1 : 0;
    int t1 = d ? T_LEN - 2 : 1;
    u16 xa  = xgp[(size_t)t0 * (BATCH * GDIM)];
    u16 xb2 = xgp[(size_t)t1 * (BATCH * GDIM)];

    float hs = 4.f / 127.f;                // h LSB for step-0 input h
    int cur = 0;
    for (int s = 0; s < T_LEN; ++s) {
        const int t = d ? (T_LEN - 1 - s) : s;
        int s2 = (s + 2 < T_LEN) ? s + 2 : T_LEN - 1;
        int t2 = d ? (T_LEN - 1 - s2) : s2;
        u16 xc = xgp[(size_t)t2 * (BATCH * GDIM)];         // prefetch s+2

        int acc0 = 0, acc1 = 0, acc2 = 0, acc3 = 0;        // 4 interleaved chains
        #pragma unroll
        for (int q4 = 0; q4 < 4; ++q4) {
            uint4 h0v = hq[cur][q4 * 4 + 0];
            uint4 h1v = hq[cur][q4 * 4 + 1];
            uint4 h2v = hq[cur][q4 * 4 + 2];
            uint4 h3v = hq[cur][q4 * 4 + 3];
            uint4 w0 = Wr[q4 * 4 + 0], w1 = Wr[q4 * 4 + 1];
            uint4 w2 = Wr[q4 * 4 + 2], w3 = Wr[q4 * 4 + 3];
            acc0 = dot4i8(w0.x, h0v.x, acc0); acc0 = dot4i8(w0.y, h0v.y, acc0);
            acc0 = dot4i8(w0.z, h0v.z, acc0); acc0 = dot4i8(w0.w, h0v.w, acc0);
            acc1 = dot4i8(w1.x, h1v.x, acc1); acc1 = dot4i8(w1.y, h1v.y, acc1);
            acc1 = dot4i8(w1.z, h1v.z, acc1); acc1 = dot4i8(w1.w, h1v.w, acc1);
            acc2 = dot4i8(w2.x, h2v.x, acc2); acc2 = dot4i8(w2.y, h2v.y, acc2);
            acc2 = dot4i8(w2.z, h2v.z, acc2); acc2 = dot4i8(w2.w, h2v.w, acc2);
            acc3 = dot4i8(w3.x, h3v.x, acc3); acc3 = dot4i8(w3.y, h3v.y, acc3);
            acc3 = dot4i8(w3.z, h3v.z, acc3); acc3 = dot4i8(w3.w, h3v.w, acc3);
        }
        int gi = (acc0 + acc1) + (acc2 + acc3);            // exact int sum, |gi| < 2^23
        float g = bf2f(xa) + (float)gi * (scl * hs);
        act[tid] = (r == 2) ? ftanh(g) : fsig(g);          // gate order i,f,g,o
        __syncthreads();                                   // act visible; h reads done
        if (tid < HDIM) {
            float iv = act[tid], fv = act[HDIM + tid], gv = act[2 * HDIM + tid], ov = act[3 * HDIM + tid];
            cst = fv * cst + iv * gv;
            float h = ov * ftanh(cst);
            XOUT[((size_t)t * BATCH + b) * EDIM + d * HDIM + tid] = f2bf(h);
            int q = (int)rintf(h * 127.f);                 // |h|<1: scale 1/127
            q = q > 127 ? 127 : (q < -127 ? -127 : q);
            ((signed char*)hq)[(cur ^ 1) * 256 + tid] = (signed char)q;
        }
        __syncthreads();                                   // new hq visible
        cur ^= 1;
        hs = 1.f / 127.f;                                  // from step 1 on
        xa = xb2; xb2 = xc;
    }
}

// ------------- feats[tb][k] = x[tb] . w_out[k] + b_out[k]  (one wave per tb) -------------
__global__ __launch_bounds__(64) void feats_k(const u16* __restrict__ X,      // [16384][512] bf16
                                              const float* __restrict__ Wout, // [7][512] f32
                                              const float* __restrict__ Bout, // [7] f32
                                              float* __restrict__ F) {        // [16384][8] f32
    int tb = blockIdx.x, lane = threadIdx.x;
    uint4 xv = ((const uint4*)(X + (size_t)tb * EDIM))[lane];   // 8 bf16 of x
    float xf[8];
    xf[0] = bflo(xv.x); xf[1] = bfhi(xv.x); xf[2] = bflo(xv.y); xf[3] = bfhi(xv.y);
    xf[4] = bflo(xv.z); xf[5] = bfhi(xv.z); xf[6] = bflo(xv.w); xf[7] = bfhi(xv.w);
    #pragma unroll
    for (int k = 0; k < KTAG; ++k) {
        const float4* wpo = (const float4*)(Wout + (size_t)k * EDIM) + lane * 2;
        float4 wa = wpo[0], wb = wpo[1];
        float p = 0.0f;
        p = fmaf(xf[0], wa.x, p); p = fmaf(xf[1], wa.y, p);
        p = fmaf(xf[2], wa.z, p); p = fmaf(xf[3], wa.w, p);
        p = fmaf(xf[4], wb.x, p); p = fmaf(xf[5], wb.y, p);
        p = fmaf(xf[6], wb.z, p); p = fmaf(xf[7], wb.w, p);
        #pragma unroll
        for (int off = 32; off > 0; off >>= 1) p += __shfl_xor(p, off, 64);
        if (lane == 0) F[tb * 8 + k] = p + Bout[k];
    }
}

// ------------- Viterbi: one wave, lane = batch; byte-packed backpointers -------------
__global__ __launch_bounds__(64) void viterbi_k(const float* __restrict__ F,
                                                const float* __restrict__ Trans, // [7][7] next,prev
                                                u64* __restrict__ BP8,           // [256][64]
                                                float* __restrict__ OUT) {       // 16448 floats
    int b = threadIdx.x;
    float tr[KTAG][KTAG];
    #pragma unroll
    for (int n = 0; n < KTAG; ++n)
        #pragma unroll
        for (int p = 0; p < KTAG; ++p)
            tr[n][p] = Trans[n * KTAG + p];

    float v[KTAG];
    #pragma unroll
    for (int k = 0; k < KTAG; ++k) v[k] = (k == 5) ? 0.0f : NEGV;  // START=5

    float cf[KTAG], nf[KTAG];
    #pragma unroll
    for (int n = 0; n < KTAG; ++n) cf[n] = F[b * 8 + n];           // t=0

    for (int t = 0; t < T_LEN; ++t) {
        int tp = (t + 1 < T_LEN) ? t + 1 : t;
        #pragma unroll
        for (int n = 0; n < KTAG; ++n) nf[n] = F[((tp)*BATCH + b) * 8 + n];  // prefetch t+1

        u64 pk = 0;
        float nv[KTAG];
        #pragma unroll
        for (int n = 0; n < KTAG; ++n) {
            float best = v[0] + tr[n][0]; int bi = 0;
            #pragma unroll
            for (int p = 1; p < KTAG; ++p) {
                float s = v[p] + tr[n][p];
                if (s > best) { best = s; bi = p; }   // strict > == np.argmax first-max
            }
            pk |= ((u64)bi) << (8 * n);
            nv[n] = best + cf[n];
        }
        BP8[t * BATCH + b] = pk;
        #pragma unroll
        for (int n = 0; n < KTAG; ++n) { v[n] = nv[n]; cf[n] = nf[n]; }
    }
    float bs = v[0] + tr[6][0]; int tag = 0;          // STOP=6
    #pragma unroll
    for (int k = 1; k < KTAG; ++k) {
        float s = v[k] + tr[6][k];
        if (s > bs) { bs = s; tag = k; }
    }
    OUT[T_LEN * BATCH + b] = bs;                      // path_score [B]
    for (int t = T_LEN - 1; t >= 0; --t) {
        OUT[(size_t)b * T_LEN + t] = (float)tag;      // best_path [B][T]
        tag = (int)((BP8[t * BATCH + b] >> (8 * tag)) & 0xff);
    }
}

extern "C" void kernel_launch(void* const* d_in, const int* in_sizes, int n_in,
                              void* d_out, int out_size, void* d_ws, size_t ws_size,
                              hipStream_t stream) {
    const int*   sent  = (const int*)d_in[0];
    const float* emb   = (const float*)d_in[1];   // [50000][512]
    const float* w_ih  = (const float*)d_in[2];   // [2][2][1024][512]
    const float* w_hh  = (const float*)d_in[3];   // [2][2][1024][256]
    const float* b_ih  = (const float*)d_in[4];   // [2][2][1024]
    const float* b_hh  = (const float*)d_in[5];
    const float* w_out = (const float*)d_in[6];   // [7][512]
    const float* b_out = (const float*)d_in[7];   // [7]
    const float* trans = (const float*)d_in[8];   // [7][7]
    const float* h0    = (const float*)d_in[9];   // [4][64][256]
    const float* c0    = (const float*)d_in[10];
    float* out = (float*)d_out;

    char* ws = (char*)d_ws;
    u16*   xg    = (u16*)(ws);                       // 64 MB  [2][16384][1024] bf16
    u16*   x     = (u16*)(ws + 67108864);            // 16 MB  [16384][512] bf16
    u16*   wihB  = (u16*)(ws + 83886080);            // 4 MB   bf16 w_ih
    uint4* wq    = (uint4*)(ws + 88080384);          // 1 MB   int8 w_hh (packed)
    float* scl   = (float*)(ws + 89128960);          // 16 KB  scales
    float* feats = (float*)(ws + 89145344);          // 512 KB
    u64*   bp8   = (u64*)(ws + 89669632);            // 128 KB

    prep_k<<<5136, 256, 0, stream>>>(sent, emb, x, w_ih, wihB, w_hh, wq, scl);

    for (int l = 0; l < 2; ++l) {
        gemm_xg<<<dim3(1024, 2), 256, 0, stream>>>(
            x, wihB + (size_t)l * 2 * GDIM * EDIM,
            b_ih + (size_t)l * 2 * GDIM, b_hh + (size_t)l * 2 * GDIM, xg);
        lstm_scan_i8<<<128, 1024, 0, stream>>>(
            xg, wq + (size_t)l * 32768, scl + (size_t)l * 2048,
            h0 + (size_t)l * 2 * BATCH * HDIM, c0 + (size_t)l * 2 * BATCH * HDIM, x);
    }

    feats_k<<<16384, 64, 0, stream>>>(x, w_out, b_out, feats);
    viterbi_k<<<1, 64, 0, stream>>>(feats, trans, bp8, out);
}

// Round 8
// 1089.571 us; speedup vs baseline: 1.0474x; 1.0474x over previous
//
#include <hip/hip_runtime.h>
#include <stdint.h>

#define T_LEN 256
#define BATCH 64
#define EDIM  512
#define HDIM  256      // hidden per direction
#define GDIM  1024     // 4*HDIM
#define KTAG  7
#define NEGV  -10000.0f

using u16 = unsigned short;
using u32 = unsigned int;
using u64 = unsigned long long;

typedef short    bf16x8 __attribute__((ext_vector_type(8)));
typedef float    f32x4  __attribute__((ext_vector_type(4)));

__device__ __forceinline__ float bflo(u32 u) { return __uint_as_float(u << 16); }
__device__ __forceinline__ float bfhi(u32 u) { return __uint_as_float(u & 0xffff0000u); }
__device__ __forceinline__ float bf2f(u16 u) { return __uint_as_float(((u32)u) << 16); }
__device__ __forceinline__ u16 f2bf(float f) {
    u32 x = __float_as_uint(f);
    u32 r = x + 0x7fffu + ((x >> 16) & 1u);   // round-to-nearest-even
    return (u16)(r >> 16);
}
__device__ __forceinline__ u32 pack2(float a, float b) {
    return (u32)f2bf(a) | ((u32)f2bf(b) << 16);
}
// fast sigmoid / tanh (rel err ~1e-5, far below bf16 input noise)
__device__ __forceinline__ float fsig(float x)  { return __builtin_amdgcn_rcpf(1.f + __expf(-x)); }
__device__ __forceinline__ float ftanh(float x) { return 1.f - 2.f * __builtin_amdgcn_rcpf(1.f + __expf(2.f * x)); }

__device__ __forceinline__ int dot4i8(int a, int b, int c) {
#if __has_builtin(__builtin_amdgcn_sdot4)
    return __builtin_amdgcn_sdot4(a, b, c, false);     // v_dot4_i32_i8 (HW path confirmed R6)
#else
    c += (int)(signed char)(a & 0xff)         * (int)(signed char)(b & 0xff);
    c += (int)(signed char)((a >> 8) & 0xff)  * (int)(signed char)((b >> 8) & 0xff);
    c += (int)(signed char)((a >> 16) & 0xff) * (int)(signed char)((b >> 16) & 0xff);
    c += (int)(signed char)(a >> 24)          * (int)(signed char)(b >> 24);
    return c;
#endif
}

// ---------- fused preprocessing: embed gather | w_ih f32->bf16 | w_hh int8 quant ----------
__global__ __launch_bounds__(256) void prep_k(const int* __restrict__ sent,
                                              const float* __restrict__ emb,
                                              u16* __restrict__ X,
                                              const float* __restrict__ Wih,
                                              u16* __restrict__ WB,
                                              const float* __restrict__ Whh,
                                              uint4* __restrict__ WQ,
                                              float* __restrict__ SCL) {
    const int blk = blockIdx.x, tid = threadIdx.x;
    if (blk < 4096) {                                // ---- embedding gather+convert ----
        int tb   = blk * 4 + (tid >> 6);
        int lane = tid & 63;
        int tok  = sent[tb];
        const float4* src = (const float4*)(emb + (size_t)tok * EDIM);
        float4 a = src[lane * 2];
        float4 b = src[lane * 2 + 1];
        uint4 o;
        o.x = pack2(a.x, a.y); o.y = pack2(a.z, a.w);
        o.z = pack2(b.x, b.y); o.w = pack2(b.z, b.w);
        ((uint4*)(X + (size_t)tb * EDIM))[lane] = o;
    } else if (blk < 5120) {                         // ---- w_ih f32 -> bf16 ----
        int g = (blk - 4096) * 256 + tid;            // 262144 groups of 8
        const float4* src = (const float4*)(Wih + (size_t)g * 8);
        float4 a = src[0], b = src[1];
        uint4 o;
        o.x = pack2(a.x, a.y); o.y = pack2(a.z, a.w);
        o.z = pack2(b.x, b.y); o.w = pack2(b.z, b.w);
        *(uint4*)(WB + (size_t)g * 8) = o;
    } else {                                         // ---- w_hh int8 row-quant ----
        int g  = (blk - 5120) * 256 + tid;           // 4096 rows
        int ld = g >> 10, row = g & 1023;
        const float* src = Whh + ((size_t)ld * GDIM + row) * HDIM;
        float m = 1e-30f;
        for (int k4 = 0; k4 < 64; ++k4) {
            float4 w = ((const float4*)src)[k4];
            m = fmaxf(m, fmaxf(fmaxf(fabsf(w.x), fabsf(w.y)), fmaxf(fabsf(w.z), fabsf(w.w))));
        }
        float inv = 127.f / m;
        SCL[ld * GDIM + row] = m / 127.f;
        int r = row >> 8, j = row & 255;
        for (int c8 = 0; c8 < 16; ++c8) {            // 16-byte chunks
            u32 dw[4];
            #pragma unroll
            for (int d4 = 0; d4 < 4; ++d4) {
                u32 p = 0;
                #pragma unroll
                for (int bb = 0; bb < 4; ++bb) {
                    float w = src[c8 * 16 + d4 * 4 + bb];
                    int q = (int)rintf(w * inv);
                    q = q > 127 ? 127 : (q < -127 ? -127 : q);
                    p |= ((u32)(q & 0xff)) << (8 * bb);
                }
                dw[d4] = p;
            }
            int half = c8 >> 3, c = c8 & 7;
            WQ[(size_t)((((ld * 4 + r) * 2 + half) * 8 + c) * 256 + j)] =
                (uint4){dw[0], dw[1], dw[2], dw[3]};
        }
    }
}

// ------------- xg = x @ w_ih^T + b_ih + b_hh  (MFMA bf16, wave computes 64x64) -------------
__global__ __launch_bounds__(256, 4) void gemm_xg(const u16* __restrict__ A,    // [16384][512] bf16
                                                  const u16* __restrict__ W,    // [2][1024][512] bf16
                                                  const float* __restrict__ Bih,// [2][1024] f32
                                                  const float* __restrict__ Bhh,
                                                  u16* __restrict__ XG) {       // [2][16384][1024] bf16
    const int d    = blockIdx.y;
    const int lane = threadIdx.x & 63;
    const int wv   = threadIdx.x >> 6;
    const int mi   = blockIdx.x >> 2;               // 0..255, shared by all 4 waves
    const int nj   = (blockIdx.x & 3) * 4 + wv;     // 0..15
    const int l15  = lane & 15;
    const int quad = lane >> 4;

    const u16* Wd = W + (size_t)d * GDIM * EDIM;
    const u16* Ap[4];
    const u16* Bp[4];
    #pragma unroll
    for (int i = 0; i < 4; ++i) {
        Ap[i] = A  + (size_t)(mi * 64 + i * 16 + l15) * EDIM + quad * 8;
        Bp[i] = Wd + (size_t)(nj * 64 + i * 16 + l15) * EDIM + quad * 8;
    }

    f32x4 acc[4][4];
    #pragma unroll
    for (int mt = 0; mt < 4; ++mt)
        #pragma unroll
        for (int nt = 0; nt < 4; ++nt)
            acc[mt][nt] = (f32x4){0.f, 0.f, 0.f, 0.f};

    for (int kk = 0; kk < 16; ++kk) {
        bf16x8 av[4], bv[4];
        #pragma unroll
        for (int i = 0; i < 4; ++i) {
            av[i] = *(const bf16x8*)(Ap[i] + kk * 32);
            bv[i] = *(const bf16x8*)(Bp[i] + kk * 32);
        }
        #pragma unroll
        for (int mt = 0; mt < 4; ++mt)
            #pragma unroll
            for (int nt = 0; nt < 4; ++nt)
                acc[mt][nt] = __builtin_amdgcn_mfma_f32_16x16x32_bf16(av[mt], bv[nt], acc[mt][nt], 0, 0, 0);
    }

    u16* xgd = XG + (size_t)d * ((size_t)16384 * GDIM);
    #pragma unroll
    for (int nt = 0; nt < 4; ++nt) {
        int col = nj * 64 + nt * 16 + l15;          // C/D: col=lane&15, row=quad*4+reg
        float bias = Bih[d * GDIM + col] + Bhh[d * GDIM + col];
        #pragma unroll
        for (int mt = 0; mt < 4; ++mt) {
            int row0 = mi * 64 + mt * 16 + quad * 4;
            #pragma unroll
            for (int r = 0; r < 4; ++r)
                xgd[(size_t)(row0 + r) * GDIM + col] = f2bf(acc[mt][nt][r] + bias);
        }
    }
}

// ------------- recurrent scan: int8 weights PINNED in registers + chunked xg via LDS -------------
// 128 blocks = (d,b); 512 threads: j = tid&255, half = tid>>8 (K-half).
// launch_bounds(512,1): only 128 blocks exist -> 1 block/CU anyway; VGPR cap 256.
// Wr[4][8] = 128 VGPRs pinned via inline-asm so LLVM cannot sink the loads into the loop
// (R7 post-mortem: VGPR_Count=48 proved it re-streamed weights from L2 every step).
// xg staged through LDS in 8-step chunks: global loads at s%8==0, ds_write at s%8==4,
// so the per-barrier vmcnt(0) drain happens once per 8 steps, not every step.
__global__ __launch_bounds__(512, 1) void lstm_scan_i8(
        const u16* __restrict__ XG,        // [2][16384][1024] bf16 (this layer)
        const uint4* __restrict__ WQ,      // this layer's int8 slice (base at ld=2l)
        const float* __restrict__ SCL,     // [2][1024] weight LSB
        const float* __restrict__ H0,      // [2][64][256] f32
        const float* __restrict__ C0,
        u16* __restrict__ XOUT) {          // [16384][512] bf16
    const int b    = blockIdx.x & 63;
    const int d    = blockIdx.x >> 6;
    const int tid  = threadIdx.x;
    const int j    = tid & 255;
    const int half = tid >> 8;
    const int wv   = tid >> 6;             // wave id 0..7
    const int lane = tid & 63;

    __shared__ uint4 hq[2][16];            // double-buffered int8 h (2 x 256 B)
    __shared__ float ps[4][256];           // half1 integer partials (exact f32)
    __shared__ u16   xgl[2][8][1024];      // 2 x 8-step xg chunks (32 KB)

    // ---- load weights into registers and PIN them ----
    uint4 Wr[4][8];
    #pragma unroll
    for (int r = 0; r < 4; ++r)
        #pragma unroll
        for (int c = 0; c < 8; ++c)
            Wr[r][c] = WQ[(size_t)((((d * 4 + r) * 2 + half) * 8 + c) * 256 + j)];
    #pragma unroll
    for (int r = 0; r < 4; ++r)
        #pragma unroll
        for (int c = 0; c < 8; ++c) {
            asm volatile("" : "+v"(Wr[r][c].x));
            asm volatile("" : "+v"(Wr[r][c].y));
            asm volatile("" : "+v"(Wr[r][c].z));
            asm volatile("" : "+v"(Wr[r][c].w));
        }
    float scl[4];
    #pragma unroll
    for (int r = 0; r < 4; ++r) scl[r] = SCL[d * GDIM + r * 256 + j];

    const u16* XGd = XG + (size_t)d * ((size_t)16384 * GDIM);

    // ---- init state ----
    float cst = 0.0f;
    if (half == 0) {
        float h0v = H0[((size_t)d * BATCH + b) * HDIM + j];
        cst       = C0[((size_t)d * BATCH + b) * HDIM + j];
        int q = (int)rintf(h0v * 31.75f);                  // scale 127/4 (|h0| can exceed 1)
        q = q > 127 ? 127 : (q < -127 ? -127 : q);
        ((signed char*)hq)[j] = (signed char)q;            // buffer 0
    }

    // ---- preload xg chunks for s=0..7 (buf0) and s=8..15 (buf1); wave wv owns chunk-row wv ----
    {
        #pragma unroll
        for (int cb = 0; cb < 2; ++cb) {
            int srow = cb * 8 + wv;
            int tg = d ? (T_LEN - 1 - srow) : srow;
            const uint4* g = (const uint4*)(XGd + ((size_t)tg * BATCH + b) * GDIM);
            uint4 pa = g[lane], pb = g[64 + lane];
            *(uint4*)&xgl[cb][wv][lane * 8]       = pa;
            *(uint4*)&xgl[cb][wv][512 + lane * 8] = pb;
        }
    }
    __syncthreads();

    uint4 xga, xgb;                        // in-flight chunk pieces (held 4 steps)
    float hs = 4.f / 127.f;                // h LSB for step-0 input h
    int cur = 0;
    for (int s = 0; s < T_LEN; ++s) {
        const int t = d ? (T_LEN - 1 - s) : s;

        if ((s & 7) == 0 && s >= 8 && s + 8 < T_LEN) {     // issue next chunk's global loads
            int srow = s + 8 + wv;
            int tg = d ? (T_LEN - 1 - srow) : srow;
            const uint4* g = (const uint4*)(XGd + ((size_t)tg * BATCH + b) * GDIM);
            xga = g[lane];
            xgb = g[64 + lane];
        }
        if ((s & 7) == 4 && s >= 12 && s + 4 < T_LEN) {    // commit to LDS (latency covered)
            int bufw = ((s + 4) >> 3) & 1;
            *(uint4*)&xgl[bufw][wv][lane * 8]       = xga;
            *(uint4*)&xgl[bufw][wv][512 + lane * 8] = xgb;
        }

        int acc0 = 0, acc1 = 0, acc2 = 0, acc3 = 0;        // 4 independent chains
        const uint4* hb = &hq[cur][half * 8];
        #pragma unroll
        for (int c = 0; c < 8; ++c) {
            uint4 hv = hb[c];                              // uniform -> LDS broadcast
            acc0 = dot4i8(Wr[0][c].x, hv.x, acc0);
            acc0 = dot4i8(Wr[0][c].y, hv.y, acc0);
            acc0 = dot4i8(Wr[0][c].z, hv.z, acc0);
            acc0 = dot4i8(Wr[0][c].w, hv.w, acc0);
            acc1 = dot4i8(Wr[1][c].x, hv.x, acc1);
            acc1 = dot4i8(Wr[1][c].y, hv.y, acc1);
            acc1 = dot4i8(Wr[1][c].z, hv.z, acc1);
            acc1 = dot4i8(Wr[1][c].w, hv.w, acc1);
            acc2 = dot4i8(Wr[2][c].x, hv.x, acc2);
            acc2 = dot4i8(Wr[2][c].y, hv.y, acc2);
            acc2 = dot4i8(Wr[2][c].z, hv.z, acc2);
            acc2 = dot4i8(Wr[2][c].w, hv.w, acc2);
            acc3 = dot4i8(Wr[3][c].x, hv.x, acc3);
            acc3 = dot4i8(Wr[3][c].y, hv.y, acc3);
            acc3 = dot4i8(Wr[3][c].z, hv.z, acc3);
            acc3 = dot4i8(Wr[3][c].w, hv.w, acc3);
        }
        if (half == 1) {                                   // |acc| < 2^22: f32-exact
            ps[0][j] = (float)acc0; ps[1][j] = (float)acc1;
            ps[2][j] = (float)acc2; ps[3][j] = (float)acc3;
        }
        __syncthreads();                                   // partials visible; h reads done
        if (half == 0) {
            const int row = s & 7, buf = (s >> 3) & 1;
            float g0 = bf2f(xgl[buf][row][j])       + ((float)acc0 + ps[0][j]) * (scl[0] * hs);
            float g1 = bf2f(xgl[buf][row][256 + j]) + ((float)acc1 + ps[1][j]) * (scl[1] * hs);
            float g2 = bf2f(xgl[buf][row][512 + j]) + ((float)acc2 + ps[2][j]) * (scl[2] * hs);
            float g3 = bf2f(xgl[buf][row][768 + j]) + ((float)acc3 + ps[3][j]) * (scl[3] * hs);
            float iv = fsig(g0), fv = fsig(g1), gv = ftanh(g2), ov = fsig(g3);
            cst = fv * cst + iv * gv;
            float h = ov * ftanh(cst);
            XOUT[((size_t)t * BATCH + b) * EDIM + d * HDIM + j] = f2bf(h);
            int q = (int)rintf(h * 127.f);                 // |h|<1: scale 1/127
            q = q > 127 ? 127 : (q < -127 ? -127 : q);
            ((signed char*)hq)[(cur ^ 1) * 256 + j] = (signed char)q;
        }
        __syncthreads();                                   // new hq (and chunk writes) visible
        cur ^= 1;
        hs = 1.f / 127.f;                                  // from step 1 on
    }
}

// ------------- feats[tb][k] = x[tb] . w_out[k] + b_out[k]  (one wave per tb) -------------
__global__ __launch_bounds__(64) void feats_k(const u16* __restrict__ X,      // [16384][512] bf16
                                              const float* __restrict__ Wout, // [7][512] f32
                                              const float* __restrict__ Bout, // [7] f32
                                              float* __restrict__ F) {        // [16384][8] f32
    int tb = blockIdx.x, lane = threadIdx.x;
    uint4 xv = ((const uint4*)(X + (size_t)tb * EDIM))[lane];   // 8 bf16 of x
    float xf[8];
    xf[0] = bflo(xv.x); xf[1] = bfhi(xv.x); xf[2] = bflo(xv.y); xf[3] = bfhi(xv.y);
    xf[4] = bflo(xv.z); xf[5] = bfhi(xv.z); xf[6] = bflo(xv.w); xf[7] = bfhi(xv.w);
    #pragma unroll
    for (int k = 0; k < KTAG; ++k) {
        const float4* wpo = (const float4*)(Wout + (size_t)k * EDIM) + lane * 2;
        float4 wa = wpo[0], wb = wpo[1];
        float p = 0.0f;
        p = fmaf(xf[0], wa.x, p); p = fmaf(xf[1], wa.y, p);
        p = fmaf(xf[2], wa.z, p); p = fmaf(xf[3], wa.w, p);
        p = fmaf(xf[4], wb.x, p); p = fmaf(xf[5], wb.y, p);
        p = fmaf(xf[6], wb.z, p); p = fmaf(xf[7], wb.w, p);
        #pragma unroll
        for (int off = 32; off > 0; off >>= 1) p += __shfl_xor(p, off, 64);
        if (lane == 0) F[tb * 8 + k] = p + Bout[k];
    }
}

// ------------- Viterbi: one wave, lane = batch; byte-packed backpointers -------------
__global__ __launch_bounds__(64) void viterbi_k(const float* __restrict__ F,
                                                const float* __restrict__ Trans, // [7][7] next,prev
                                                u64* __restrict__ BP8,           // [256][64]
                                                float* __restrict__ OUT) {       // 16448 floats
    int b = threadIdx.x;
    float tr[KTAG][KTAG];
    #pragma unroll
    for (int n = 0; n < KTAG; ++n)
        #pragma unroll
        for (int p = 0; p < KTAG; ++p)
            tr[n][p] = Trans[n * KTAG + p];

    float v[KTAG];
    #pragma unroll
    for (int k = 0; k < KTAG; ++k) v[k] = (k == 5) ? 0.0f : NEGV;  // START=5

    float cf[KTAG], nf[KTAG];
    #pragma unroll
    for (int n = 0; n < KTAG; ++n) cf[n] = F[b * 8 + n];           // t=0

    for (int t = 0; t < T_LEN; ++t) {
        int tp = (t + 1 < T_LEN) ? t + 1 : t;
        #pragma unroll
        for (int n = 0; n < KTAG; ++n) nf[n] = F[((tp)*BATCH + b) * 8 + n];  // prefetch t+1

        u64 pk = 0;
        float nv[KTAG];
        #pragma unroll
        for (int n = 0; n < KTAG; ++n) {
            float best = v[0] + tr[n][0]; int bi = 0;
            #pragma unroll
            for (int p = 1; p < KTAG; ++p) {
                float s = v[p] + tr[n][p];
                if (s > best) { best = s; bi = p; }   // strict > == np.argmax first-max
            }
            pk |= ((u64)bi) << (8 * n);
            nv[n] = best + cf[n];
        }
        BP8[t * BATCH + b] = pk;
        #pragma unroll
        for (int n = 0; n < KTAG; ++n) { v[n] = nv[n]; cf[n] = nf[n]; }
    }
    float bs = v[0] + tr[6][0]; int tag = 0;          // STOP=6
    #pragma unroll
    for (int k = 1; k < KTAG; ++k) {
        float s = v[k] + tr[6][k];
        if (s > bs) { bs = s; tag = k; }
    }
    OUT[T_LEN * BATCH + b] = bs;                      // path_score [B]
    for (int t = T_LEN - 1; t >= 0; --t) {
        OUT[(size_t)b * T_LEN + t] = (float)tag;      // best_path [B][T]
        tag = (int)((BP8[t * BATCH + b] >> (8 * tag)) & 0xff);
    }
}

extern "C" void kernel_launch(void* const* d_in, const int* in_sizes, int n_in,
                              void* d_out, int out_size, void* d_ws, size_t ws_size,
                              hipStream_t stream) {
    const int*   sent  = (const int*)d_in[0];
    const float* emb   = (const float*)d_in[1];   // [50000][512]
    const float* w_ih  = (const float*)d_in[2];   // [2][2][1024][512]
    const float* w_hh  = (const float*)d_in[3];   // [2][2][1024][256]
    const float* b_ih  = (const float*)d_in[4];   // [2][2][1024]
    const float* b_hh  = (const float*)d_in[5];
    const float* w_out = (const float*)d_in[6];   // [7][512]
    const float* b_out = (const float*)d_in[7];   // [7]
    const float* trans = (const float*)d_in[8];   // [7][7]
    const float* h0    = (const float*)d_in[9];   // [4][64][256]
    const float* c0    = (const float*)d_in[10];
    float* out = (float*)d_out;

    char* ws = (char*)d_ws;
    u16*   xg    = (u16*)(ws);                       // 64 MB  [2][16384][1024] bf16
    u16*   x     = (u16*)(ws + 67108864);            // 16 MB  [16384][512] bf16
    u16*   wihB  = (u16*)(ws + 83886080);            // 4 MB   bf16 w_ih
    uint4* wq    = (uint4*)(ws + 88080384);          // 1 MB   int8 w_hh (packed)
    float* scl   = (float*)(ws + 89128960);          // 16 KB  scales
    float* feats = (float*)(ws + 89145344);          // 512 KB
    u64*   bp8   = (u64*)(ws + 89669632);            // 128 KB

    prep_k<<<5136, 256, 0, stream>>>(sent, emb, x, w_ih, wihB, w_hh, wq, scl);

    for (int l = 0; l < 2; ++l) {
        gemm_xg<<<dim3(1024, 2), 256, 0, stream>>>(
            x, wihB + (size_t)l * 2 * GDIM * EDIM,
            b_ih + (size_t)l * 2 * GDIM, b_hh + (size_t)l * 2 * GDIM, xg);
        lstm_scan_i8<<<128, 512, 0, stream>>>(
            xg, wq + (size_t)l * 32768, scl + (size_t)l * 2048,
            h0 + (size_t)l * 2 * BATCH * HDIM, c0 + (size_t)l * 2 * BATCH * HDIM, x);
    }

    feats_k<<<16384, 64, 0, stream>>>(x, w_out, b_out, feats);
    viterbi_k<<<1, 64, 0, stream>>>(feats, trans, bp8, out);
}